// Round 4
// baseline (116.382 us; speedup 1.0000x reference)
//
#include <hip/hip_runtime.h>

#define NB 16
#define T 16000
#define NF 64
#define TILE 252              // output timesteps per block
#define TT 256                // threads per block
#define HALO 32
#define ROWS (TILE + HALO)    // 284
#define RSU 36                // combined row stride in dwords: L dw 0..15, R dw 16..31, pad 4
#define N_ITD 16
#define N_ILD 8
#define NSTG ((ROWS * 4 + TT - 1) / TT)   // 5 staging iterations (last partial)

typedef _Float16 half2_t __attribute__((ext_vector_type(2)));

__device__ __forceinline__ unsigned int pk2h(float a, float b) {
    half2_t h;
    h.x = (_Float16)a;
    h.y = (_Float16)b;
    return __builtin_bit_cast(unsigned int, h);
}
__device__ __forceinline__ float dot2(unsigned int a, unsigned int b, float c) {
    return __builtin_amdgcn_fdot2(__builtin_bit_cast(half2_t, a),
                                  __builtin_bit_cast(half2_t, b), c, false);
}

// LDS = 284*36*4 = 40896 B -> 4 blocks/CU = 16 waves/CU
__global__ __launch_bounds__(TT, 4) void biaural_kernel(const float* __restrict__ L,
                                                        const float* __restrict__ R,
                                                        float* __restrict__ out) {
    __shared__ unsigned int sh[ROWS * RSU];

    const int b = blockIdx.y;
    // XCD swizzle: gridX=64, 8x8 transpose -> each XCD gets 8 consecutive t-tiles
    const int p = blockIdx.x;
    const int lx = (p & 7) * 8 + (p >> 3);
    const int t0 = lx * TILE;
    const int tid = threadIdx.x;

    const float* __restrict__ Lb = L + (size_t)b * T * NF;
    const float* __restrict__ Rb = R + (size_t)b * T * NF;

    float acc[N_ITD];
#pragma unroll
    for (int i = 0; i < N_ITD; ++i) acc[i] = 0.f;
    float sumL = 0.f, sumR = 0.f;

    const int OFF[8] = {2, 6, 11, 15, 19, 23, 28, 32};
    const unsigned int ONE2 = 0x3C003C00u;   // (1.0h, 1.0h)
    const int ct = (tid < TILE) ? tid : (TILE - 1);   // clamp idle threads into bounds
    const int crowbase = (HALO + ct) * RSU;

#pragma unroll
    for (int pass = 0; pass < 2; ++pass) {
        const int pf = pass * 32;            // float offset within the 64-ch row
        if (pass) __syncthreads();           // protect LDS reuse

        // ---- stage [t0-32, t0+TILE-1] x 32ch of both ears as f16.
        // Unconditional clamped loads + mask-select: no control flow in the
        // hot 4 iterations -> all global loads issued before first ds_write.
#pragma unroll
        for (int it = 0; it < NSTG; ++it) {
            const int n = tid + it * TT;
            if (n < ROWS * 4) {              // compile-time true for it<4
                const int row = n >> 2;
                const int cf = (n & 3) * 8;  // float offset of 8-float chunk
                const int gt = t0 - HALO + row;
                const int gtc = (gt < 0) ? 0 : ((gt >= T) ? (T - 1) : gt);
                const unsigned int vm = (gt >= 0 && gt < T) ? 0xFFFFFFFFu : 0u;
                const float* lp = Lb + (size_t)gtc * NF + pf + cf;
                const float* rp = Rb + (size_t)gtc * NF + pf + cf;
                const float4 a0 = *(const float4*)lp;
                const float4 a1 = *(const float4*)(lp + 4);
                const float4 b0 = *(const float4*)rp;
                const float4 b1 = *(const float4*)(rp + 4);
                uint4 pl = make_uint4(pk2h(a0.x, a0.y) & vm, pk2h(a0.z, a0.w) & vm,
                                      pk2h(a1.x, a1.y) & vm, pk2h(a1.z, a1.w) & vm);
                uint4 pr = make_uint4(pk2h(b0.x, b0.y) & vm, pk2h(b0.z, b0.w) & vm,
                                      pk2h(b1.x, b1.y) & vm, pk2h(b1.z, b1.w) & vm);
                const int idx = row * RSU + (n & 3) * 4;
                *(uint4*)&sh[idx] = pl;
                *(uint4*)&sh[idx + 16] = pr;
            }
        }
        __syncthreads();

        // ---- compute: 4 chunks of 8 channels
#pragma unroll
        for (int c = 0; c < 4; ++c) {
            const uint4 lc = *(const uint4*)&sh[crowbase + c * 4];
            const uint4 rc = *(const uint4*)&sh[crowbase + 16 + c * 4];
            sumL = dot2(lc.x, ONE2, sumL); sumL = dot2(lc.y, ONE2, sumL);
            sumL = dot2(lc.z, ONE2, sumL); sumL = dot2(lc.w, ONE2, sumL);
            sumR = dot2(rc.x, ONE2, sumR); sumR = dot2(rc.y, ONE2, sumR);
            sumR = dot2(rc.z, ONE2, sumR); sumR = dot2(rc.w, ONE2, sumR);
#pragma unroll
            for (int k = 0; k < 8; ++k) {
                const int rb = crowbase - OFF[k] * RSU;
                const uint4 la = *(const uint4*)&sh[rb + c * 4];
                acc[8 + k] = dot2(la.x, rc.x, acc[8 + k]);
                acc[8 + k] = dot2(la.y, rc.y, acc[8 + k]);
                acc[8 + k] = dot2(la.z, rc.z, acc[8 + k]);
                acc[8 + k] = dot2(la.w, rc.w, acc[8 + k]);
                const uint4 ra = *(const uint4*)&sh[rb + 16 + c * 4];
                acc[7 - k] = dot2(lc.x, ra.x, acc[7 - k]);
                acc[7 - k] = dot2(lc.y, ra.y, acc[7 - k]);
                acc[7 - k] = dot2(lc.z, ra.z, acc[7 - k]);
                acc[7 - k] = dot2(lc.w, ra.w, acc[7 - k]);
            }
        }
    }

    const int t = t0 + tid;
    if (tid < TILE && t < T) {
        // ---- ITD: [B,T,16]
        float* oitd = out + ((size_t)b * T + t) * N_ITD;
#pragma unroll
        for (int q = 0; q < 4; ++q) {
            *(float4*)(oitd + q * 4) =
                make_float4(acc[q * 4 + 0], acc[q * 4 + 1], acc[q * 4 + 2], acc[q * 4 + 3]);
        }

        // ---- ILD: [B,T,8] after the ITD block
        const float ild = (sumL - sumR) / (sumL + sumR + 1e-6f);
        const float PREFS[8] = {-1.f, -0.71428573f, -0.42857143f, -0.14285714f,
                                0.14285715f, 0.42857143f, 0.71428573f, 1.f};
        float ov[8];
#pragma unroll
        for (int j = 0; j < 8; ++j) {
            const float z = (ild - PREFS[j]) * (1.0f / 0.3f);
            ov[j] = __expf(-0.5f * z * z);
        }
        float* oild = out + (size_t)NB * T * N_ITD + ((size_t)b * T + t) * N_ILD;
        *(float4*)(oild + 0) = make_float4(ov[0], ov[1], ov[2], ov[3]);
        *(float4*)(oild + 4) = make_float4(ov[4], ov[5], ov[6], ov[7]);
    }
}

extern "C" void kernel_launch(void* const* d_in, const int* in_sizes, int n_in,
                              void* d_out, int out_size, void* d_ws, size_t ws_size,
                              hipStream_t stream) {
    const float* L = (const float*)d_in[0];
    const float* R = (const float*)d_in[1];
    float* out = (float*)d_out;
    dim3 grid(64, NB);   // 64*252 >= 16000; 8x8 XCD swizzle assumes gridX==64
    biaural_kernel<<<grid, dim3(TT), 0, stream>>>(L, R, out);
}